// Round 4
// baseline (346.897 us; speedup 1.0000x reference)
//
#include <hip/hip_runtime.h>

#define NPTS   8192
#define CCH    32
#define LDIM   64
#define ODIM   128
#define KNN    16
#define QPB    64                  // queries per block (16 per wave = MFMA tile rows)
#define TILEC  128                 // candidates per LDS tile
#define NTIL   (NPTS / TILEC)      // 64
#define NBLK   ((4 * NPTS) / QPB)  // 512 blocks
#define SCAP   56                  // survivor capacity per query (analysis: worst ~40)
#define MARGIN 0.75f               // >= 2*eps bound for fp16 distance error

typedef _Float16 half8   __attribute__((ext_vector_type(8)));
typedef float    float4v __attribute__((ext_vector_type(4)));

// 512-thread block = 8 waves = 2 wave-groups. Group g scans tiles of parity g
// (32 tiles each) with its own double-buffer pair. Tile order staggered by
// blockIdx so 512 blocks don't hit the same L2 lines simultaneously.
//
// __launch_bounds__(512, 2): second arg acts as min-BLOCKS/CU on this
// toolchain (round-3 evidence: (512,4) forced VGPR=64 = 512/(4*8/4 waves/EU)
// and spilled kd[]/ki[] to scratch, +90 MB HBM traffic). 2 blocks/CU -> VGPR
// cap 128, no spills, same occupancy cap as before.
//
// LDS map:
//  scan:   buf[g][p] @ (g*2+p)*8704, 4 x 8704 = 34816  (8192 xh + 512 sq each)
//          slist @34816 (14336) | scnt @49152 (256) | tq @49408 (256) | kn @49664 (4096)
//          t32 overlay @0 (16384) after pass-1 (consumed before pass-2 staging)
//  pass3:  skeys overlay @0 (14336)   (stage bufs dead)
//  epilog: pl @0 (8448) | hh @8704 (16640)   (kn alive @49664)
#define LDS_BYTES 53760
#define OFF_SQ   8192              // sq row offset inside a stage buffer
#define OFF_SL   34816
#define OFF_SC   49152
#define OFF_TQ   49408
#define OFF_KN   49664
#define OFF_HH   8704

__device__ __forceinline__ void gload_lds16(const void* g, void* l) {
    __builtin_amdgcn_global_load_lds(
        (const __attribute__((address_space(1))) unsigned int*)g,
        (__attribute__((address_space(3))) unsigned int*)l, 16, 0, 0);
}
__device__ __forceinline__ void gload_lds4(const void* g, void* l) {
    __builtin_amdgcn_global_load_lds(
        (const __attribute__((address_space(1))) unsigned int*)g,
        (__attribute__((address_space(3))) unsigned int*)l, 4, 0, 0);
}

// Prologue: squared norms (same summation order -> identical bits) and fp16
// candidates written ONCE in B-fragment order:
//   point p, channel c=q*8+j -> half8 index (p>>7)*512 + ((p>>4)&7)*64 + (p&15), quad q stride 16
__global__ void prep_kernel(const float* __restrict__ x, float* __restrict__ sqg,
                            _Float16* __restrict__ xh) {
    int p = blockIdx.x * 256 + threadIdx.x;      // 0..32767
    const float4* src = (const float4*)(x + (size_t)p * CCH);
    float4 f[8];
    #pragma unroll
    for (int k = 0; k < 8; ++k) f[k] = src[k];
    float s = 0.f;
    #pragma unroll
    for (int k = 0; k < 8; ++k)
        s += f[k].x * f[k].x + f[k].y * f[k].y + f[k].z * f[k].z + f[k].w * f[k].w;
    sqg[p] = s;
    half8* dst = (half8*)xh + ((p >> 7) * 512 + ((p >> 4) & 7) * 64 + (p & 15));
    #pragma unroll
    for (int q = 0; q < 4; ++q) {
        float4 a = f[2 * q], c = f[2 * q + 1];
        half8 h;
        h[0] = (_Float16)a.x; h[1] = (_Float16)a.y; h[2] = (_Float16)a.z; h[3] = (_Float16)a.w;
        h[4] = (_Float16)c.x; h[5] = (_Float16)c.y; h[6] = (_Float16)c.z; h[7] = (_Float16)c.w;
        dst[q * 16] = h;                          // quad stride = 128 halfs = 16 half8
    }
}

__global__ __launch_bounds__(512, 2)
void graph_layer_kernel(const float* __restrict__ x,
                        const float* __restrict__ sqg,
                        const _Float16* __restrict__ xh,
                        const float* __restrict__ Wl,
                        const float* __restrict__ bl,
                        const float* __restrict__ Wc,
                        const float* __restrict__ bc,
                        float* __restrict__ out)
{
    __shared__ __align__(16) char smem[LDS_BYTES];
    int*   slist = (int*)(smem + OFF_SL);
    float* t32   = (float*)smem;               // overlay on stage bufs, post-pass-1
    int*   scnt  = (int*)(smem + OFF_SC);
    float* tq    = (float*)(smem + OFF_TQ);
    float* skeys = (float*)smem;               // pass-3 overlay
    int*   kn    = (int*)(smem + OFF_KN);
    float* pl    = (float*)smem;               // epilogue overlays
    float* hh    = (float*)(smem + OFF_HH);

    const int tid  = threadIdx.x;
    const int lane = tid & 63;
    const int w    = tid >> 6;                 // 0..7
    const int g    = w >> 2;                   // wave group: 0 = even tiles, 1 = odd
    const int lw   = w & 3;                    // wave within group
    const int col  = lane & 15;                // candidate column / A-frag row
    const int quad = lane >> 4;
    const float INF = __builtin_inff();

    const int qb0 = blockIdx.x * QPB;
    const int b   = qb0 >> 13;
    const int qbl = qb0 & (NPTS - 1);
    const int S   = blockIdx.x & 31;           // tile-order stagger
    const float* xb  = x   + (size_t)(b << 13) * CCH;
    const float* sqb = sqg + (b << 13);
    const char*  xhb = (const char*)xh + (size_t)b * NTIL * 8192;

    // ---- A-fragment from fp16 workspace: A[m=col][k=quad*8+j], queries lw*16+col
    half8 qh;
    {
        int p = qb0 + lw * 16 + col;
        qh = *(const half8*)((const char*)xh
              + (size_t)(p >> 7) * 8192 + ((p >> 4) & 7) * 1024
              + quad * 256 + (p & 15) * 16);
    }

    auto tileof = [&](int I) { return (((I + S) & 31) << 1) | g; };
    auto bufat  = [&](int I) { return smem + (((g << 1) | (I & 1)) * 8704); };

    // async stage of super-iter I's tile for this group: 8KB fp16 + 512B sq
    auto stage = [&](int I) {
        char* sb = bufat(I);
        int tile = tileof(I);
        const char* src = xhb + (size_t)tile * 8192;
        int tg = tid & 255;                     // thread index within group
        gload_lds16(src + tg * 16,        sb + lw * 1024);   // lds = base + lane*16
        gload_lds16(src + 4096 + tg * 16, sb + 4096 + lw * 1024);
        if (lw < 2)
            gload_lds4(sqb + tile * TILEC + lw * 64 + lane, sb + OFF_SQ + lw * 256);
    };

    // ================= PASS 1: branch-free per-lane top-2 per query ==========
    float m1[4] = {INF, INF, INF, INF};
    float m2[4] = {INF, INF, INF, INF};

    stage(0);
    __syncthreads();
    #pragma unroll 1
    for (int I = 0; I < 32; ++I) {
        if (I + 1 < 32) stage(I + 1);
        const char*  cb = bufat(I);
        const float* sv = (const float*)(cb + OFF_SQ);
        #pragma unroll
        for (int st = 0; st < 8; ++st) {
            half8 bh = *(const half8*)(cb + st * 1024 + lane * 16);   // conflict-free
            float sc = sv[st * 16 + col];
            float4v acc = __builtin_amdgcn_mfma_f32_16x16x32_f16(
                qh, bh, (float4v){0.f, 0.f, 0.f, 0.f}, 0, 0, 0);
            #pragma unroll
            for (int j = 0; j < 4; ++j) {
                float key = fmaf(-2.f, acc[j], sc);
                float o1  = m1[j];
                m1[j] = fminf(key, o1);
                // 2nd-smallest of {key, o1, m2} == min(m2, max(key, o1)) given o1<=m2
                m2[j] = __builtin_amdgcn_fmed3f(key, o1, m2[j]);
            }
        }
        __syncthreads();
    }

    // ---- per-query threshold: 16th smallest of the 64-value union ----
    // (32 partitions x top-2; finer than before -> threshold <= old one, SCAP analysis holds)
    #pragma unroll
    for (int j = 0; j < 4; ++j) {
        int qq = lw * 16 + quad * 4 + j;
        t32[qq * 64 + g * 32 + col * 2 + 0] = m1[j];
        t32[qq * 64 + g * 32 + col * 2 + 1] = m2[j];
    }
    __syncthreads();
    if (tid < QPB) {
        float kd[KNN];
        #pragma unroll
        for (int p = 0; p < KNN; ++p) kd[p] = INF;
        for (int i = 0; i < 64; ++i) {
            float ck = t32[tid * 64 + i];
            if (ck < kd[KNN - 1]) {
                #pragma unroll
                for (int p = 0; p < KNN; ++p) {
                    bool sw = ck < kd[p];
                    float nk = sw ? ck : kd[p];
                    ck = sw ? kd[p] : ck;
                    kd[p] = nk;
                }
            }
        }
        tq[tid] = kd[KNN - 1];
        scnt[tid] = 0;
    }
    __syncthreads();
    float T2[4];
    #pragma unroll
    for (int j = 0; j < 4; ++j) T2[j] = tq[lw * 16 + quad * 4 + j] + MARGIN;

    // ================= PASS 2: rescan, atomic survivor append ==========
    stage(0);
    __syncthreads();
    #pragma unroll 1
    for (int I = 0; I < 32; ++I) {
        if (I + 1 < 32) stage(I + 1);
        const char*  cb = bufat(I);
        const float* sv = (const float*)(cb + OFF_SQ);
        int tbase = tileof(I) * TILEC;
        #pragma unroll
        for (int st = 0; st < 8; ++st) {
            half8 bh = *(const half8*)(cb + st * 1024 + lane * 16);
            float sc = sv[st * 16 + col];
            float4v acc = __builtin_amdgcn_mfma_f32_16x16x32_f16(
                qh, bh, (float4v){0.f, 0.f, 0.f, 0.f}, 0, 0, 0);
            #pragma unroll
            for (int j = 0; j < 4; ++j) {
                float key = fmaf(-2.f, acc[j], sc);
                if (key < T2[j]) {
                    int qq = lw * 16 + quad * 4 + j;
                    int slot = atomicAdd(&scnt[qq], 1);
                    if (slot < SCAP)
                        slist[qq * SCAP + slot] = tbase + st * 16 + col;
                }
            }
        }
        __syncthreads();
    }

    // ================= PASS 3: exact fp32 re-check of survivors ==========
    {
        int qq = tid & 63, sb8 = tid >> 6;     // 8 workers per query
        int n = scnt[qq]; if (n > SCAP) n = SCAP;
        const float4* xi4 = (const float4*)(xb + (size_t)(qbl + qq) * CCH);
        for (int s = sb8; s < n; s += 8) {
            int jdx = slist[qq * SCAP + s];
            const float4* xj = (const float4*)(xb + (size_t)jdx * CCH);
            float a0 = 0.f, a1 = 0.f, a2 = 0.f, a3 = 0.f;
            #pragma unroll
            for (int k = 0; k < 8; ++k) {
                float4 cv = xj[k], qv = xi4[k];
                a0 = fmaf(cv.x, qv.x, a0); a1 = fmaf(cv.y, qv.y, a1);
                a2 = fmaf(cv.z, qv.z, a2); a3 = fmaf(cv.w, qv.w, a3);
            }
            float dot = (a0 + a1) + (a2 + a3);
            skeys[qq * SCAP + s] = fmaf(-2.f, dot, sqb[jdx]);
        }
    }
    __syncthreads();
    if (tid < QPB) {      // exact (key, idx) top-16; slist is UNORDERED -> full lex compare
        int n = scnt[tid]; if (n > SCAP) n = SCAP;
        float kd[KNN]; int ki[KNN];
        #pragma unroll
        for (int p = 0; p < KNN; ++p) { kd[p] = INF; ki[p] = 0x7fffffff; }
        for (int s = 0; s < n; ++s) {
            float ck = skeys[tid * SCAP + s];
            int   cj = slist[tid * SCAP + s];
            if (ck < kd[KNN-1] || (ck == kd[KNN-1] && cj < ki[KNN-1])) {
                #pragma unroll
                for (int p = 0; p < KNN; ++p) {
                    bool sw = (ck < kd[p]) || (ck == kd[p] && cj < ki[p]);
                    float nk = sw ? ck : kd[p];
                    int   nj = sw ? cj : ki[p];
                    ck = sw ? kd[p] : ck;
                    cj = sw ? ki[p] : cj;
                    kd[p] = nk; ki[p] = nj;
                }
            }
        }
        #pragma unroll
        for (int r = 0; r < KNN; ++r) kn[tid * KNN + r] = ki[r];
    }
    __syncthreads();

    // ================= epilogue: gather + max-pool + MLP ==========
    {
        int q = tid >> 3, part = tid & 7;      // 8 threads/query, one float4 each
        float4 m0 = make_float4(-INF, -INF, -INF, -INF);
        #pragma unroll
        for (int k = 0; k < KNN; ++k) {
            int j = kn[q * KNN + k];
            float4 v = *(const float4*)(xb + (size_t)j * CCH + part * 4);
            m0.x = fmaxf(m0.x, v.x); m0.y = fmaxf(m0.y, v.y);
            m0.z = fmaxf(m0.z, v.z); m0.w = fmaxf(m0.w, v.w);
        }
        float* d = pl + q * 33 + part * 4;
        d[0] = m0.x; d[1] = m0.y; d[2] = m0.z; d[3] = m0.w;
    }
    __syncthreads();
    {
        int l = tid & 63, qg2 = tid >> 6;      // 8 query-slices
        #pragma unroll 1
        for (int qq = qg2; qq < QPB; qq += 8) {
            float acc = bl[l];
            #pragma unroll
            for (int c = 0; c < CCH; ++c)
                acc = fmaf(pl[qq * 33 + c], Wl[c * LDIM + l], acc);
            hh[qq * 65 + l] = acc;
        }
    }
    __syncthreads();
    {
        int o = tid & 127, qh2 = tid >> 7;     // 4 query-slices
        #pragma unroll 1
        for (int qq = qh2; qq < QPB; qq += 4) {
            float acc = bc[o];
            #pragma unroll
            for (int l = 0; l < LDIM; ++l)
                acc = fmaf(hh[qq * 65 + l], Wc[l * ODIM + o], acc);
            out[(size_t)(qb0 + qq) * ODIM + o] = fmaxf(acc, 0.f);
        }
    }
}

extern "C" void kernel_launch(void* const* d_in, const int* in_sizes, int n_in,
                              void* d_out, int out_size, void* d_ws, size_t ws_size,
                              hipStream_t stream) {
    const float* x  = (const float*)d_in[0];
    const float* Wl = (const float*)d_in[1];
    const float* bl = (const float*)d_in[2];
    const float* Wc = (const float*)d_in[3];
    const float* bc = (const float*)d_in[4];
    float* out = (float*)d_out;
    float*    sqf = (float*)d_ws;                       // 32768 fp32 = 128 KB
    _Float16* xh  = (_Float16*)((char*)d_ws + 131072);  // 32768 x 32 fp16 = 2 MB, frag-order
    (void)in_sizes; (void)n_in; (void)out_size; (void)ws_size;

    hipLaunchKernelGGL(prep_kernel, dim3((4 * NPTS) / 256), dim3(256), 0, stream, x, sqf, xh);
    hipLaunchKernelGGL(graph_layer_kernel, dim3(NBLK), dim3(512), 0, stream,
                       x, sqf, xh, Wl, bl, Wc, bc, out);
}

// Round 5
// 247.414 us; speedup vs baseline: 1.4021x; 1.4021x over previous
//
#include <hip/hip_runtime.h>

#define NPTS   8192
#define CCH    32
#define LDIM   64
#define ODIM   128
#define KNN    16
#define QPB    64                  // queries per block (16 per wave = MFMA tile rows)
#define TILEC  128                 // candidates per LDS tile
#define NTIL   (NPTS / TILEC)      // 64
#define NBLK   ((4 * NPTS) / QPB)  // 512 blocks
#define SCAP   57                  // survivor capacity (worst ~40); 57 = odd stride -> conflict-free rank reads
#define MARGIN 0.75f               // >= 2*eps bound for fp16 distance error
#define T32STR 65                  // t32 row stride (odd -> conflict-free column reads)

typedef _Float16 half8   __attribute__((ext_vector_type(8)));
typedef float    float4v __attribute__((ext_vector_type(4)));

// 512-thread block = 8 waves = 2 wave-groups; group g scans tiles of parity g
// with its own double-buffer pair. Tile order staggered by blockIdx.
//
// OCCUPANCY MODEL (round-3/4 evidence): waves/SIMD steps at VGPR {64,128,256}
// (m69). VGPR=64 -> 8 waves/SIMD -> 3 blocks/CU (LDS-capped); VGPR=84 -> 4
// waves/SIMD -> 2 blocks/CU and 30% slower. So: __launch_bounds__(512,4)
// forces the 64-reg budget, and the per-thread kd[16]/ki[16] selection arrays
// (the only >64 pressure, which spilled 90 MB in round 3) are replaced by
// rank-based selection over LDS (exact, ~20 live VGPRs).
//
// LDS map:
//  scan:   buf[g][p] @ (g*2+p)*8704, 4 x 8704 = 34816  (8192 xh + 512 sq each)
//          slist @34816 (64*57*4 = 14592) | scnt @49408 (256) | tq @49664 (256)
//          kn @49920 (4096)  -> total 54016 (3 blocks/CU: 162048 <= 163840)
//          t32 overlay @0 (64*65*4 = 16640) after pass-1 (dead before pass-2 staging)
//  pass3:  skeys overlay @0 (14592)   (stage bufs dead)
//  epilog: pl @0 (8448) | hh @8704 (16640)   (kn alive @49920)
#define LDS_BYTES 54016
#define OFF_SQ   8192              // sq row offset inside a stage buffer
#define OFF_SL   34816
#define OFF_SC   49408
#define OFF_TQ   49664
#define OFF_KN   49920
#define OFF_HH   8704

__device__ __forceinline__ void gload_lds16(const void* g, void* l) {
    __builtin_amdgcn_global_load_lds(
        (const __attribute__((address_space(1))) unsigned int*)g,
        (__attribute__((address_space(3))) unsigned int*)l, 16, 0, 0);
}
__device__ __forceinline__ void gload_lds4(const void* g, void* l) {
    __builtin_amdgcn_global_load_lds(
        (const __attribute__((address_space(1))) unsigned int*)g,
        (__attribute__((address_space(3))) unsigned int*)l, 4, 0, 0);
}

// Prologue: squared norms (same summation order -> identical bits) and fp16
// candidates written ONCE in B-fragment order:
//   point p, channel c=q*8+j -> half8 index (p>>7)*512 + ((p>>4)&7)*64 + (p&15), quad q stride 16
__global__ void prep_kernel(const float* __restrict__ x, float* __restrict__ sqg,
                            _Float16* __restrict__ xh) {
    int p = blockIdx.x * 256 + threadIdx.x;      // 0..32767
    const float4* src = (const float4*)(x + (size_t)p * CCH);
    float4 f[8];
    #pragma unroll
    for (int k = 0; k < 8; ++k) f[k] = src[k];
    float s = 0.f;
    #pragma unroll
    for (int k = 0; k < 8; ++k)
        s += f[k].x * f[k].x + f[k].y * f[k].y + f[k].z * f[k].z + f[k].w * f[k].w;
    sqg[p] = s;
    half8* dst = (half8*)xh + ((p >> 7) * 512 + ((p >> 4) & 7) * 64 + (p & 15));
    #pragma unroll
    for (int q = 0; q < 4; ++q) {
        float4 a = f[2 * q], c = f[2 * q + 1];
        half8 h;
        h[0] = (_Float16)a.x; h[1] = (_Float16)a.y; h[2] = (_Float16)a.z; h[3] = (_Float16)a.w;
        h[4] = (_Float16)c.x; h[5] = (_Float16)c.y; h[6] = (_Float16)c.z; h[7] = (_Float16)c.w;
        dst[q * 16] = h;                          // quad stride = 128 halfs = 16 half8
    }
}

__global__ __launch_bounds__(512, 4)
void graph_layer_kernel(const float* __restrict__ x,
                        const float* __restrict__ sqg,
                        const _Float16* __restrict__ xh,
                        const float* __restrict__ Wl,
                        const float* __restrict__ bl,
                        const float* __restrict__ Wc,
                        const float* __restrict__ bc,
                        float* __restrict__ out)
{
    __shared__ __align__(16) char smem[LDS_BYTES];
    int*   slist = (int*)(smem + OFF_SL);
    float* t32   = (float*)smem;               // overlay on stage bufs, post-pass-1
    int*   scnt  = (int*)(smem + OFF_SC);
    float* tq    = (float*)(smem + OFF_TQ);
    float* skeys = (float*)smem;               // pass-3 overlay
    int*   kn    = (int*)(smem + OFF_KN);
    float* pl    = (float*)smem;               // epilogue overlays
    float* hh    = (float*)(smem + OFF_HH);

    const int tid  = threadIdx.x;
    const int lane = tid & 63;
    const int w    = tid >> 6;                 // 0..7
    const int g    = w >> 2;                   // wave group: 0 = even tiles, 1 = odd
    const int lw   = w & 3;                    // wave within group
    const int col  = lane & 15;                // candidate column / A-frag row
    const int quad = lane >> 4;
    const float INF = __builtin_inff();

    const int qb0 = blockIdx.x * QPB;
    const int b   = qb0 >> 13;
    const int qbl = qb0 & (NPTS - 1);
    const int S   = blockIdx.x & 31;           // tile-order stagger
    const float* xb  = x   + (size_t)(b << 13) * CCH;
    const float* sqb = sqg + (b << 13);
    const char*  xhb = (const char*)xh + (size_t)b * NTIL * 8192;

    // ---- A-fragment from fp16 workspace: A[m=col][k=quad*8+j], queries lw*16+col
    half8 qh;
    {
        int p = qb0 + lw * 16 + col;
        qh = *(const half8*)((const char*)xh
              + (size_t)(p >> 7) * 8192 + ((p >> 4) & 7) * 1024
              + quad * 256 + (p & 15) * 16);
    }

    auto tileof = [&](int I) { return (((I + S) & 31) << 1) | g; };
    auto bufat  = [&](int I) { return smem + (((g << 1) | (I & 1)) * 8704); };

    // async stage of super-iter I's tile for this group: 8KB fp16 + 512B sq
    auto stage = [&](int I) {
        char* sb = bufat(I);
        int tile = tileof(I);
        const char* src = xhb + (size_t)tile * 8192;
        int tg = tid & 255;                     // thread index within group
        gload_lds16(src + tg * 16,        sb + lw * 1024);   // lds = base + lane*16
        gload_lds16(src + 4096 + tg * 16, sb + 4096 + lw * 1024);
        if (lw < 2)
            gload_lds4(sqb + tile * TILEC + lw * 64 + lane, sb + OFF_SQ + lw * 256);
    };

    // ================= PASS 1: branch-free per-lane top-2 per query ==========
    float m1[4] = {INF, INF, INF, INF};
    float m2[4] = {INF, INF, INF, INF};

    stage(0);
    __syncthreads();
    #pragma unroll 1
    for (int I = 0; I < 32; ++I) {
        if (I + 1 < 32) stage(I + 1);
        const char*  cb = bufat(I);
        const float* sv = (const float*)(cb + OFF_SQ);
        #pragma unroll
        for (int st = 0; st < 8; ++st) {
            half8 bh = *(const half8*)(cb + st * 1024 + lane * 16);   // conflict-free
            float sc = sv[st * 16 + col];
            float4v acc = __builtin_amdgcn_mfma_f32_16x16x32_f16(
                qh, bh, (float4v){0.f, 0.f, 0.f, 0.f}, 0, 0, 0);
            #pragma unroll
            for (int j = 0; j < 4; ++j) {
                float key = fmaf(-2.f, acc[j], sc);
                float o1  = m1[j];
                m1[j] = fminf(key, o1);
                // 2nd-smallest of {key, o1, m2} == min(m2, max(key, o1)) given o1<=m2
                m2[j] = __builtin_amdgcn_fmed3f(key, o1, m2[j]);
            }
        }
        __syncthreads();
    }

    // ---- per-query threshold: 16th smallest of the 64-value union ----
    // Rank-based (exact, lex tie-break): rank(i) = #{j : v_j < v_i or (==, j<i)}.
    // Ranks are a permutation of 0..63 -> exactly one rank-15 writer per query.
    #pragma unroll
    for (int j = 0; j < 4; ++j) {
        int qq = lw * 16 + quad * 4 + j;
        t32[qq * T32STR + g * 32 + col * 2 + 0] = m1[j];
        t32[qq * T32STR + g * 32 + col * 2 + 1] = m2[j];
    }
    __syncthreads();
    {
        int q  = tid & 63;                     // query
        int wt = tid >> 6;                     // worker 0..7, items wt*8..wt*8+7
        float v[8]; int r[8];
        #pragma unroll
        for (int u = 0; u < 8; ++u) { v[u] = t32[q * T32STR + wt * 8 + u]; r[u] = 0; }
        for (int jj = 0; jj < 64; ++jj) {
            float vj = t32[q * T32STR + jj];   // odd stride -> 2-way max, no conflicts
            #pragma unroll
            for (int u = 0; u < 8; ++u)
                r[u] += (int)(vj < v[u]) | ((int)(vj == v[u]) & (int)(jj < wt * 8 + u));
        }
        #pragma unroll
        for (int u = 0; u < 8; ++u)
            if (r[u] == KNN - 1) tq[q] = v[u];
        if (tid < QPB) scnt[tid] = 0;
    }
    __syncthreads();
    float T2[4];
    #pragma unroll
    for (int j = 0; j < 4; ++j) T2[j] = tq[lw * 16 + quad * 4 + j] + MARGIN;

    // ================= PASS 2: rescan, atomic survivor append ==========
    stage(0);
    __syncthreads();
    #pragma unroll 1
    for (int I = 0; I < 32; ++I) {
        if (I + 1 < 32) stage(I + 1);
        const char*  cb = bufat(I);
        const float* sv = (const float*)(cb + OFF_SQ);
        int tbase = tileof(I) * TILEC;
        #pragma unroll
        for (int st = 0; st < 8; ++st) {
            half8 bh = *(const half8*)(cb + st * 1024 + lane * 16);
            float sc = sv[st * 16 + col];
            float4v acc = __builtin_amdgcn_mfma_f32_16x16x32_f16(
                qh, bh, (float4v){0.f, 0.f, 0.f, 0.f}, 0, 0, 0);
            #pragma unroll
            for (int j = 0; j < 4; ++j) {
                float key = fmaf(-2.f, acc[j], sc);
                if (key < T2[j]) {
                    int qq = lw * 16 + quad * 4 + j;
                    int slot = atomicAdd(&scnt[qq], 1);
                    if (slot < SCAP)
                        slist[qq * SCAP + slot] = tbase + st * 16 + col;
                }
            }
        }
        __syncthreads();
    }

    // ================= PASS 3: exact fp32 re-check of survivors ==========
    {
        int qq = tid & 63, sb8 = tid >> 6;     // 8 workers per query
        int n = scnt[qq]; if (n > SCAP) n = SCAP;
        const float4* xi4 = (const float4*)(xb + (size_t)(qbl + qq) * CCH);
        for (int s = sb8; s < n; s += 8) {
            int jdx = slist[qq * SCAP + s];
            const float4* xj = (const float4*)(xb + (size_t)jdx * CCH);
            float a0 = 0.f, a1 = 0.f, a2 = 0.f, a3 = 0.f;
            #pragma unroll
            for (int k = 0; k < 8; ++k) {
                float4 cv = xj[k], qv = xi4[k];
                a0 = fmaf(cv.x, qv.x, a0); a1 = fmaf(cv.y, qv.y, a1);
                a2 = fmaf(cv.z, qv.z, a2); a3 = fmaf(cv.w, qv.w, a3);
            }
            float dot = (a0 + a1) + (a2 + a3);
            skeys[qq * SCAP + s] = fmaf(-2.f, dot, sqb[jdx]);
        }
    }
    __syncthreads();
    // ---- exact top-16 set via rank (lex on (key, idx)); kn order = rank, set exact.
    // n >= 16 guaranteed (threshold >= true 16th + MARGIN covers fp16 error).
    {
        int q  = tid & 63;
        int wt = tid >> 6;
        int n = scnt[q]; if (n > SCAP) n = SCAP;
        for (int s = wt; s < n; s += 8) {
            float k = skeys[q * SCAP + s];
            int   i = slist[q * SCAP + s];
            int rank = 0;
            for (int jj = 0; jj < n; ++jj) {
                float kj = skeys[q * SCAP + jj];   // stride 57 -> conflict-free
                int   ij = slist[q * SCAP + jj];
                rank += (int)(kj < k) | ((int)(kj == k) & (int)(ij < i));
            }
            if (rank < KNN) kn[q * KNN + rank] = i;
        }
    }
    __syncthreads();

    // ================= epilogue: gather + max-pool + MLP ==========
    {
        int q = tid >> 3, part = tid & 7;      // 8 threads/query, one float4 each
        float4 m0 = make_float4(-INF, -INF, -INF, -INF);
        #pragma unroll
        for (int k = 0; k < KNN; ++k) {
            int j = kn[q * KNN + k];
            float4 v = *(const float4*)(xb + (size_t)j * CCH + part * 4);
            m0.x = fmaxf(m0.x, v.x); m0.y = fmaxf(m0.y, v.y);
            m0.z = fmaxf(m0.z, v.z); m0.w = fmaxf(m0.w, v.w);
        }
        float* d = pl + q * 33 + part * 4;
        d[0] = m0.x; d[1] = m0.y; d[2] = m0.z; d[3] = m0.w;
    }
    __syncthreads();
    {
        int l = tid & 63, qg2 = tid >> 6;      // 8 query-slices
        #pragma unroll 1
        for (int qq = qg2; qq < QPB; qq += 8) {
            float acc = bl[l];
            #pragma unroll
            for (int c = 0; c < CCH; ++c)
                acc = fmaf(pl[qq * 33 + c], Wl[c * LDIM + l], acc);
            hh[qq * 65 + l] = acc;
        }
    }
    __syncthreads();
    {
        int o = tid & 127, qh2 = tid >> 7;     // 4 query-slices
        #pragma unroll 1
        for (int qq = qh2; qq < QPB; qq += 4) {
            float acc = bc[o];
            #pragma unroll
            for (int l = 0; l < LDIM; ++l)
                acc = fmaf(hh[qq * 65 + l], Wc[l * ODIM + o], acc);
            out[(size_t)(qb0 + qq) * ODIM + o] = fmaxf(acc, 0.f);
        }
    }
}

extern "C" void kernel_launch(void* const* d_in, const int* in_sizes, int n_in,
                              void* d_out, int out_size, void* d_ws, size_t ws_size,
                              hipStream_t stream) {
    const float* x  = (const float*)d_in[0];
    const float* Wl = (const float*)d_in[1];
    const float* bl = (const float*)d_in[2];
    const float* Wc = (const float*)d_in[3];
    const float* bc = (const float*)d_in[4];
    float* out = (float*)d_out;
    float*    sqf = (float*)d_ws;                       // 32768 fp32 = 128 KB
    _Float16* xh  = (_Float16*)((char*)d_ws + 131072);  // 32768 x 32 fp16 = 2 MB, frag-order
    (void)in_sizes; (void)n_in; (void)out_size; (void)ws_size;

    hipLaunchKernelGGL(prep_kernel, dim3((4 * NPTS) / 256), dim3(256), 0, stream, x, sqf, xh);
    hipLaunchKernelGGL(graph_layer_kernel, dim3(NBLK), dim3(512), 0, stream,
                       x, sqf, xh, Wl, bl, Wc, bc, out);
}

// Round 6
// 241.170 us; speedup vs baseline: 1.4384x; 1.0259x over previous
//
#include <hip/hip_runtime.h>

#define NPTS   8192
#define CCH    32
#define LDIM   64
#define ODIM   128
#define KNN    16
#define QPB    64                  // queries per block (16 per wave = MFMA tile rows)
#define TILEC  128                 // candidates per LDS tile
#define NTIL   (NPTS / TILEC)      // 64
#define NBLK   ((4 * NPTS) / QPB)  // 512 blocks
#define SCAP   57                  // survivor capacity (worst ~40); odd stride -> conflict-free rank reads
#define MARGIN 0.75f               // >= 2*eps bound for fp16 distance error
#define T32STR 65                  // t32 row stride (odd -> conflict-free column reads)

typedef _Float16 half8   __attribute__((ext_vector_type(8)));
typedef float    float4v __attribute__((ext_vector_type(4)));

// 512-thread block = 8 waves = 2 wave-groups; group g scans tiles of parity g
// with its own double-buffer pair. Tile order staggered by blockIdx.
//
// REGISTER MODEL (R3-R5 evidence): __launch_bounds__(512,4) -> 64-VGPR budget
// -> 8 waves/SIMD eligible -> residency 2 blocks/CU (grid-capped) = 16 waves/CU,
// ~2x the 84-VGPR rung. R5 showed ~90 MB of scratch traffic remained: the
// fully-unrolled load batches in pass-3 / gather / MLP (32-64 loads clustered)
// fit at 84 regs but spill at 64. Fix: unroll LIMITS on those phases so no
// batch exceeds ~8-16 regs. Scan loop untouched (proven 64-reg codegen).
//
// LDS map:
//  scan:   buf[g][p] @ (g*2+p)*8704, 4 x 8704 = 34816  (8192 xh + 512 sq each)
//          slist @34816 (64*57*4 = 14592) | scnt @49408 (256) | tq @49664 (256)
//          kn @49920 (4096)  -> total 54016 (3 blocks/CU LDS-wise)
//          t32 overlay @0 (64*65*4 = 16640) after pass-1 (dead before pass-2 staging)
//  pass3:  skeys overlay @0 (14592)   (stage bufs dead)
//  epilog: pl @0 (8448) | hh @8704 (16640)   (kn alive @49920)
#define LDS_BYTES 54016
#define OFF_SQ   8192              // sq row offset inside a stage buffer
#define OFF_SL   34816
#define OFF_SC   49408
#define OFF_TQ   49664
#define OFF_KN   49920
#define OFF_HH   8704

__device__ __forceinline__ void gload_lds16(const void* g, void* l) {
    __builtin_amdgcn_global_load_lds(
        (const __attribute__((address_space(1))) unsigned int*)g,
        (__attribute__((address_space(3))) unsigned int*)l, 16, 0, 0);
}
__device__ __forceinline__ void gload_lds4(const void* g, void* l) {
    __builtin_amdgcn_global_load_lds(
        (const __attribute__((address_space(1))) unsigned int*)g,
        (__attribute__((address_space(3))) unsigned int*)l, 4, 0, 0);
}

// Prologue: squared norms (same summation order -> identical bits) and fp16
// candidates written ONCE in B-fragment order:
//   point p, channel c=q*8+j -> half8 index (p>>7)*512 + ((p>>4)&7)*64 + (p&15), quad q stride 16
__global__ void prep_kernel(const float* __restrict__ x, float* __restrict__ sqg,
                            _Float16* __restrict__ xh) {
    int p = blockIdx.x * 256 + threadIdx.x;      // 0..32767
    const float4* src = (const float4*)(x + (size_t)p * CCH);
    float4 f[8];
    #pragma unroll
    for (int k = 0; k < 8; ++k) f[k] = src[k];
    float s = 0.f;
    #pragma unroll
    for (int k = 0; k < 8; ++k)
        s += f[k].x * f[k].x + f[k].y * f[k].y + f[k].z * f[k].z + f[k].w * f[k].w;
    sqg[p] = s;
    half8* dst = (half8*)xh + ((p >> 7) * 512 + ((p >> 4) & 7) * 64 + (p & 15));
    #pragma unroll
    for (int q = 0; q < 4; ++q) {
        float4 a = f[2 * q], c = f[2 * q + 1];
        half8 h;
        h[0] = (_Float16)a.x; h[1] = (_Float16)a.y; h[2] = (_Float16)a.z; h[3] = (_Float16)a.w;
        h[4] = (_Float16)c.x; h[5] = (_Float16)c.y; h[6] = (_Float16)c.z; h[7] = (_Float16)c.w;
        dst[q * 16] = h;                          // quad stride = 128 halfs = 16 half8
    }
}

__global__ __launch_bounds__(512, 4)
void graph_layer_kernel(const float* __restrict__ x,
                        const float* __restrict__ sqg,
                        const _Float16* __restrict__ xh,
                        const float* __restrict__ Wl,
                        const float* __restrict__ bl,
                        const float* __restrict__ Wc,
                        const float* __restrict__ bc,
                        float* __restrict__ out)
{
    __shared__ __align__(16) char smem[LDS_BYTES];
    int*   slist = (int*)(smem + OFF_SL);
    float* t32   = (float*)smem;               // overlay on stage bufs, post-pass-1
    int*   scnt  = (int*)(smem + OFF_SC);
    float* tq    = (float*)(smem + OFF_TQ);
    float* skeys = (float*)smem;               // pass-3 overlay
    int*   kn    = (int*)(smem + OFF_KN);
    float* pl    = (float*)smem;               // epilogue overlays
    float* hh    = (float*)(smem + OFF_HH);

    const int tid  = threadIdx.x;
    const int lane = tid & 63;
    const int w    = tid >> 6;                 // 0..7
    const int g    = w >> 2;                   // wave group: 0 = even tiles, 1 = odd
    const int lw   = w & 3;                    // wave within group
    const int col  = lane & 15;                // candidate column / A-frag row
    const int quad = lane >> 4;
    const float INF = __builtin_inff();

    const int qb0 = blockIdx.x * QPB;
    const int b   = qb0 >> 13;
    const int qbl = qb0 & (NPTS - 1);
    const int S   = blockIdx.x & 31;           // tile-order stagger
    const float* xb  = x   + (size_t)(b << 13) * CCH;
    const float* sqb = sqg + (b << 13);
    const char*  xhb = (const char*)xh + (size_t)b * NTIL * 8192;

    // ---- A-fragment from fp16 workspace: A[m=col][k=quad*8+j], queries lw*16+col
    half8 qh;
    {
        int p = qb0 + lw * 16 + col;
        qh = *(const half8*)((const char*)xh
              + (size_t)(p >> 7) * 8192 + ((p >> 4) & 7) * 1024
              + quad * 256 + (p & 15) * 16);
    }

    auto tileof = [&](int I) { return (((I + S) & 31) << 1) | g; };
    auto bufat  = [&](int I) { return smem + (((g << 1) | (I & 1)) * 8704); };

    // async stage of super-iter I's tile for this group: 8KB fp16 + 512B sq
    auto stage = [&](int I) {
        char* sb = bufat(I);
        int tile = tileof(I);
        const char* src = xhb + (size_t)tile * 8192;
        int tg = tid & 255;                     // thread index within group
        gload_lds16(src + tg * 16,        sb + lw * 1024);   // lds = base + lane*16
        gload_lds16(src + 4096 + tg * 16, sb + 4096 + lw * 1024);
        if (lw < 2)
            gload_lds4(sqb + tile * TILEC + lw * 64 + lane, sb + OFF_SQ + lw * 256);
    };

    // ================= PASS 1: branch-free per-lane top-2 per query ==========
    float m1[4] = {INF, INF, INF, INF};
    float m2[4] = {INF, INF, INF, INF};

    stage(0);
    __syncthreads();
    #pragma unroll 1
    for (int I = 0; I < 32; ++I) {
        if (I + 1 < 32) stage(I + 1);
        const char*  cb = bufat(I);
        const float* sv = (const float*)(cb + OFF_SQ);
        #pragma unroll
        for (int st = 0; st < 8; ++st) {
            half8 bh = *(const half8*)(cb + st * 1024 + lane * 16);   // conflict-free
            float sc = sv[st * 16 + col];
            float4v acc = __builtin_amdgcn_mfma_f32_16x16x32_f16(
                qh, bh, (float4v){0.f, 0.f, 0.f, 0.f}, 0, 0, 0);
            #pragma unroll
            for (int j = 0; j < 4; ++j) {
                float key = fmaf(-2.f, acc[j], sc);
                float o1  = m1[j];
                m1[j] = fminf(key, o1);
                // 2nd-smallest of {key, o1, m2} == min(m2, max(key, o1)) given o1<=m2
                m2[j] = __builtin_amdgcn_fmed3f(key, o1, m2[j]);
            }
        }
        __syncthreads();
    }

    // ---- per-query threshold: 16th smallest of the 64-value union ----
    // Rank-based (exact, lex tie-break): rank(i) = #{j : v_j < v_i or (==, j<i)}.
    // Ranks are a permutation of 0..63 -> exactly one rank-15 writer per query.
    #pragma unroll
    for (int j = 0; j < 4; ++j) {
        int qq = lw * 16 + quad * 4 + j;
        t32[qq * T32STR + g * 32 + col * 2 + 0] = m1[j];
        t32[qq * T32STR + g * 32 + col * 2 + 1] = m2[j];
    }
    __syncthreads();
    {
        int q  = tid & 63;                     // query
        int wt = tid >> 6;                     // worker 0..7, items wt*8..wt*8+7
        float v[8]; int r[8];
        #pragma unroll
        for (int u = 0; u < 8; ++u) { v[u] = t32[q * T32STR + wt * 8 + u]; r[u] = 0; }
        #pragma unroll 8
        for (int jj = 0; jj < 64; ++jj) {
            float vj = t32[q * T32STR + jj];   // odd stride -> 2-way max, no conflicts
            #pragma unroll
            for (int u = 0; u < 8; ++u)
                r[u] += (int)(vj < v[u]) | ((int)(vj == v[u]) & (int)(jj < wt * 8 + u));
        }
        #pragma unroll
        for (int u = 0; u < 8; ++u)
            if (r[u] == KNN - 1) tq[q] = v[u];
        if (tid < QPB) scnt[tid] = 0;
    }
    __syncthreads();
    float T2[4];
    #pragma unroll
    for (int j = 0; j < 4; ++j) T2[j] = tq[lw * 16 + quad * 4 + j] + MARGIN;

    // ================= PASS 2: rescan, atomic survivor append ==========
    stage(0);
    __syncthreads();
    #pragma unroll 1
    for (int I = 0; I < 32; ++I) {
        if (I + 1 < 32) stage(I + 1);
        const char*  cb = bufat(I);
        const float* sv = (const float*)(cb + OFF_SQ);
        int tbase = tileof(I) * TILEC;
        #pragma unroll
        for (int st = 0; st < 8; ++st) {
            half8 bh = *(const half8*)(cb + st * 1024 + lane * 16);
            float sc = sv[st * 16 + col];
            float4v acc = __builtin_amdgcn_mfma_f32_16x16x32_f16(
                qh, bh, (float4v){0.f, 0.f, 0.f, 0.f}, 0, 0, 0);
            #pragma unroll
            for (int j = 0; j < 4; ++j) {
                float key = fmaf(-2.f, acc[j], sc);
                if (key < T2[j]) {
                    int qq = lw * 16 + quad * 4 + j;
                    int slot = atomicAdd(&scnt[qq], 1);
                    if (slot < SCAP)
                        slist[qq * SCAP + slot] = tbase + st * 16 + col;
                }
            }
        }
        __syncthreads();
    }

    // ================= PASS 3: exact fp32 re-check of survivors ==========
    // unroll 2 keeps the live set ~20 regs (query row re-read from L1 per chunk
    // instead of hoisting 32 regs across the s-loop -> no spill at 64-VGPR budget)
    {
        int qq = tid & 63, sb8 = tid >> 6;     // 8 workers per query
        int n = scnt[qq]; if (n > SCAP) n = SCAP;
        const float4* xi4 = (const float4*)(xb + (size_t)(qbl + qq) * CCH);
        for (int s = sb8; s < n; s += 8) {
            int jdx = slist[qq * SCAP + s];
            const float4* xj = (const float4*)(xb + (size_t)jdx * CCH);
            float a0 = 0.f, a1 = 0.f, a2 = 0.f, a3 = 0.f;
            #pragma unroll 2
            for (int k = 0; k < 8; ++k) {
                float4 cv = xj[k], qv = xi4[k];
                a0 = fmaf(cv.x, qv.x, a0); a1 = fmaf(cv.y, qv.y, a1);
                a2 = fmaf(cv.z, qv.z, a2); a3 = fmaf(cv.w, qv.w, a3);
            }
            float dot = (a0 + a1) + (a2 + a3);
            skeys[qq * SCAP + s] = fmaf(-2.f, dot, sqb[jdx]);
        }
    }
    __syncthreads();
    // ---- exact top-16 set via rank (lex on (key, idx)); kn order = rank, set exact.
    // n >= 16 guaranteed (threshold >= true 16th + MARGIN covers fp16 error).
    {
        int q  = tid & 63;
        int wt = tid >> 6;
        int n = scnt[q]; if (n > SCAP) n = SCAP;
        for (int s = wt; s < n; s += 8) {
            float k = skeys[q * SCAP + s];
            int   i = slist[q * SCAP + s];
            int rank = 0;
            #pragma unroll 4
            for (int jj = 0; jj < n; ++jj) {
                float kj = skeys[q * SCAP + jj];   // stride 57 -> conflict-free
                int   ij = slist[q * SCAP + jj];
                rank += (int)(kj < k) | ((int)(kj == k) & (int)(ij < i));
            }
            if (rank < KNN) kn[q * KNN + rank] = i;
        }
    }
    __syncthreads();

    // ================= epilogue: gather + max-pool + MLP ==========
    {
        int q = tid >> 3, part = tid & 7;      // 8 threads/query, one float4 each
        float4 m0 = make_float4(-INF, -INF, -INF, -INF);
        #pragma unroll 4
        for (int k = 0; k < KNN; ++k) {
            int j = kn[q * KNN + k];
            float4 v = *(const float4*)(xb + (size_t)j * CCH + part * 4);
            m0.x = fmaxf(m0.x, v.x); m0.y = fmaxf(m0.y, v.y);
            m0.z = fmaxf(m0.z, v.z); m0.w = fmaxf(m0.w, v.w);
        }
        float* d = pl + q * 33 + part * 4;
        d[0] = m0.x; d[1] = m0.y; d[2] = m0.z; d[3] = m0.w;
    }
    __syncthreads();
    {
        int l = tid & 63, qg2 = tid >> 6;      // 8 query-slices
        #pragma unroll 1
        for (int qq = qg2; qq < QPB; qq += 8) {
            float acc = bl[l];
            #pragma unroll 8
            for (int c = 0; c < CCH; ++c)
                acc = fmaf(pl[qq * 33 + c], Wl[c * LDIM + l], acc);
            hh[qq * 65 + l] = acc;
        }
    }
    __syncthreads();
    {
        int o = tid & 127, qh2 = tid >> 7;     // 4 query-slices
        #pragma unroll 1
        for (int qq = qh2; qq < QPB; qq += 4) {
            float acc = bc[o];
            #pragma unroll 8
            for (int l = 0; l < LDIM; ++l)
                acc = fmaf(hh[qq * 65 + l], Wc[l * ODIM + o], acc);
            out[(size_t)(qb0 + qq) * ODIM + o] = fmaxf(acc, 0.f);
        }
    }
}

extern "C" void kernel_launch(void* const* d_in, const int* in_sizes, int n_in,
                              void* d_out, int out_size, void* d_ws, size_t ws_size,
                              hipStream_t stream) {
    const float* x  = (const float*)d_in[0];
    const float* Wl = (const float*)d_in[1];
    const float* bl = (const float*)d_in[2];
    const float* Wc = (const float*)d_in[3];
    const float* bc = (const float*)d_in[4];
    float* out = (float*)d_out;
    float*    sqf = (float*)d_ws;                       // 32768 fp32 = 128 KB
    _Float16* xh  = (_Float16*)((char*)d_ws + 131072);  // 32768 x 32 fp16 = 2 MB, frag-order
    (void)in_sizes; (void)n_in; (void)out_size; (void)ws_size;

    hipLaunchKernelGGL(prep_kernel, dim3((4 * NPTS) / 256), dim3(256), 0, stream, x, sqf, xh);
    hipLaunchKernelGGL(graph_layer_kernel, dim3(NBLK), dim3(512), 0, stream,
                       x, sqf, xh, Wl, bl, Wc, bc, out);
}